// Round 1
// baseline (888.148 us; speedup 1.0000x reference)
//
#include <hip/hip_runtime.h>
#include <hip/hip_bf16.h>

// Problem constants (reference: InterpretableMultiHeadAttention)
#define NHEAD  8
#define DHEAD  64
#define HIDDEN 512
#define SEQ_T  2048
#define BATCH  4
#define NQKV   1088          // (2*8+1)*64
#define QK_SCALE 0.125f      // 64^-0.5

// ---------------------------------------------------------------------------
// Kernel 1: qkv = x @ W_qkv    X:(8192,512)  W:(512,1088)  Y:(8192,1088)
// 128x64 tile, 256 threads, 8x4 register tile per thread, K-chunks of 16.
// ---------------------------------------------------------------------------
__global__ __launch_bounds__(256) void qkv_gemm(const float* __restrict__ X,
                                                const float* __restrict__ W,
                                                float* __restrict__ Y) {
  __shared__ float As[16][136];  // [kk][m], pad 136 keeps float4 alignment
  __shared__ float Bs[16][68];   // [kk][n]
  const int bm = blockIdx.x;     // 0..63
  const int bn = blockIdx.y;     // 0..16
  const int tid = threadIdx.x;
  const int tx = tid & 15;       // col group: cols tx*4..+4
  const int ty = tid >> 4;       // row group: rows ty*8..+8
  const float* xblk = X + (size_t)bm * 128 * HIDDEN;
  const float* wblk = W + bn * 64;

  float acc[8][4];
#pragma unroll
  for (int i = 0; i < 8; ++i)
#pragma unroll
    for (int j = 0; j < 4; ++j) acc[i][j] = 0.f;

  for (int k0 = 0; k0 < HIDDEN; k0 += 16) {
    // A tile: 128 rows x 16 k = 512 float4, 2 per thread
    float4 av[2];
#pragma unroll
    for (int i = 0; i < 2; ++i) {
      int f = tid + i * 256;        // 0..511
      int m = f >> 2;               // 0..127
      int kk = (f & 3) * 4;
      av[i] = *(const float4*)(xblk + (size_t)m * HIDDEN + k0 + kk);
    }
    // B tile: 16 k x 64 n = 256 float4, 1 per thread
    const int bkk = tid >> 4;       // 0..15
    const int bn0 = (tid & 15) * 4;
    float4 bv = *(const float4*)(wblk + (size_t)(k0 + bkk) * NQKV + bn0);

    __syncthreads();                // prior iteration finished reading LDS
#pragma unroll
    for (int i = 0; i < 2; ++i) {
      int f = tid + i * 256;
      int m = f >> 2;
      int kk = (f & 3) * 4;
      As[kk + 0][m] = av[i].x;
      As[kk + 1][m] = av[i].y;
      As[kk + 2][m] = av[i].z;
      As[kk + 3][m] = av[i].w;
    }
    *(float4*)&Bs[bkk][bn0] = bv;
    __syncthreads();

#pragma unroll
    for (int kk = 0; kk < 16; ++kk) {
      float4 a0 = *(const float4*)&As[kk][ty * 8];
      float4 a1 = *(const float4*)&As[kk][ty * 8 + 4];
      float4 b4 = *(const float4*)&Bs[kk][tx * 4];
      float am[8] = {a0.x, a0.y, a0.z, a0.w, a1.x, a1.y, a1.z, a1.w};
      float bb[4] = {b4.x, b4.y, b4.z, b4.w};
#pragma unroll
      for (int i = 0; i < 8; ++i)
#pragma unroll
        for (int j = 0; j < 4; ++j) acc[i][j] += am[i] * bb[j];
    }
  }

#pragma unroll
  for (int i = 0; i < 8; ++i) {
    int row = bm * 128 + ty * 8 + i;
    float4 v = make_float4(acc[i][0], acc[i][1], acc[i][2], acc[i][3]);
    *(float4*)(Y + (size_t)row * NQKV + bn * 64 + tx * 4) = v;
  }
}

// ---------------------------------------------------------------------------
// Kernel 2: flash-style causal attention, shared V across heads.
// Block = (b*8+h, qtile). 64 q-rows per block, 256 threads:
//   thread t -> q-row r = t/4, quarter cq = t%3..  (cq = t&3)
//   scores: cols c = 4j+cq (j=0..15);  acc: d = cq*16..+16
// Online softmax state (m,l) replicated across each 4-lane row group.
// P overlaid on Ks LDS after a barrier (52 KB total -> 3 blocks/CU).
// ---------------------------------------------------------------------------
__global__ __launch_bounds__(256) void attn_kernel(const float* __restrict__ qkv,
                                                   float* __restrict__ attn_out) {
  const int bh = blockIdx.x;       // 0..31
  const int qt = blockIdx.y;       // 0..31
  const int b = bh >> 3;
  const int h = bh & 7;
  const int tid = threadIdx.x;
  const int r  = tid >> 2;         // 0..63
  const int cq = tid & 3;          // 0..3

  __shared__ float Qs[64][68];
  __shared__ float Ks[64][68];     // reused as P[r][c] after score phase
  __shared__ float Vs[64][68];

  const int q0 = qt * 64;
  const float* base = qkv + (size_t)b * SEQ_T * NQKV;

  // load Q tile (rows q0..q0+63, head h)
#pragma unroll
  for (int i = 0; i < 4; ++i) {
    int f = tid + i * 256;         // 0..1023
    int m = f >> 4;                // 0..63
    int d4 = (f & 15) * 4;
    float4 v = *(const float4*)(base + (size_t)(q0 + m) * NQKV + h * 64 + d4);
    *(float4*)&Qs[m][d4] = v;
  }

  float acc[16];
#pragma unroll
  for (int i = 0; i < 16; ++i) acc[i] = 0.f;
  float m_run = -1e30f;
  float l_run = 0.f;

  for (int kt = 0; kt <= qt; ++kt) {
    const int k0 = kt * 64;
    __syncthreads();               // done reading P(=Ks)/Vs from prior tile
#pragma unroll
    for (int i = 0; i < 4; ++i) {
      int f = tid + i * 256;
      int m = f >> 4;
      int d4 = (f & 15) * 4;
      float4 kv = *(const float4*)(base + (size_t)(k0 + m) * NQKV + 512 + h * 64 + d4);
      *(float4*)&Ks[m][d4] = kv;
      float4 vv = *(const float4*)(base + (size_t)(k0 + m) * NQKV + 1024 + d4);
      *(float4*)&Vs[m][d4] = vv;
    }
    __syncthreads();

    // ---- scores: s[j] = Q[r,:] . K[4j+cq,:]
    float s[16];
#pragma unroll
    for (int j = 0; j < 16; ++j) s[j] = 0.f;
#pragma unroll
    for (int d4 = 0; d4 < 64; d4 += 4) {
      float4 q4 = *(const float4*)&Qs[r][d4];
#pragma unroll
      for (int j = 0; j < 16; ++j) {
        int c = j * 4 + cq;
        float4 k4 = *(const float4*)&Ks[c][d4];
        s[j] += q4.x * k4.x + q4.y * k4.y + q4.z * k4.z + q4.w * k4.w;
      }
    }

    // ---- mask + scale + row max
    float mloc = -1e30f;
#pragma unroll
    for (int j = 0; j < 16; ++j) {
      int cg = k0 + j * 4 + cq;
      s[j] = (cg <= q0 + r) ? s[j] * QK_SCALE : -1e30f;
      mloc = fmaxf(mloc, s[j]);
    }
    mloc = fmaxf(mloc, __shfl_xor(mloc, 1));
    mloc = fmaxf(mloc, __shfl_xor(mloc, 2));
    const float m_new = fmaxf(m_run, mloc);
    const float alpha = __expf(m_run - m_new);

    float p[16];
    float psum = 0.f;
#pragma unroll
    for (int j = 0; j < 16; ++j) {
      p[j] = __expf(s[j] - m_new);
      psum += p[j];
    }
    psum += __shfl_xor(psum, 1);
    psum += __shfl_xor(psum, 2);
    l_run = l_run * alpha + psum;
    m_run = m_new;
#pragma unroll
    for (int i = 0; i < 16; ++i) acc[i] *= alpha;

    __syncthreads();               // everyone done reading Ks as K
#pragma unroll
    for (int j = 0; j < 16; ++j) Ks[r][j * 4 + cq] = p[j];  // P[r][c]
    __syncthreads();

    // ---- acc[d] += sum_c P[r][c] * V[c][d],  d = cq*16 + i
#pragma unroll
    for (int c = 0; c < 64; ++c) {
      float pc = Ks[r][c];
      float4 v0 = *(const float4*)&Vs[c][cq * 16];
      float4 v1 = *(const float4*)&Vs[c][cq * 16 + 4];
      float4 v2 = *(const float4*)&Vs[c][cq * 16 + 8];
      float4 v3 = *(const float4*)&Vs[c][cq * 16 + 12];
      acc[0]  += pc * v0.x; acc[1]  += pc * v0.y; acc[2]  += pc * v0.z; acc[3]  += pc * v0.w;
      acc[4]  += pc * v1.x; acc[5]  += pc * v1.y; acc[6]  += pc * v1.z; acc[7]  += pc * v1.w;
      acc[8]  += pc * v2.x; acc[9]  += pc * v2.y; acc[10] += pc * v2.z; acc[11] += pc * v2.w;
      acc[12] += pc * v3.x; acc[13] += pc * v3.y; acc[14] += pc * v3.z; acc[15] += pc * v3.w;
    }
  }

  const float inv = 1.0f / l_run;
  const size_t obase = ((size_t)bh * SEQ_T + q0 + r) * DHEAD + cq * 16;
#pragma unroll
  for (int k = 0; k < 4; ++k) {
    float4 o = make_float4(acc[k * 4 + 0] * inv, acc[k * 4 + 1] * inv,
                           acc[k * 4 + 2] * inv, acc[k * 4 + 3] * inv);
    *(float4*)(attn_out + obase + k * 4) = o;
  }
}

// ---------------------------------------------------------------------------
// Kernel 3: out = mean_h(attn_vec) @ W_out
// attn:(32, 2048, 64) as (b*8+h, t, d);  Wout:(64,512);  out:(8192,512)
// Block handles 16 (b,t) rows; W_out read once per block (d-outer loop).
// ---------------------------------------------------------------------------
__global__ __launch_bounds__(256) void out_gemm(const float* __restrict__ attn,
                                                const float* __restrict__ Wout,
                                                float* __restrict__ out) {
  const int row0 = blockIdx.x * 16;   // global row = b*2048 + t
  const int tid = threadIdx.x;
  __shared__ float Ms[16][64];

#pragma unroll
  for (int i = 0; i < 4; ++i) {
    int f = tid + i * 256;            // 0..1023
    int lr = f >> 6;                  // 0..15
    int d = f & 63;
    int row = row0 + lr;
    int b = row >> 11;
    int t = row & 2047;
    float sum = 0.f;
#pragma unroll
    for (int hh = 0; hh < NHEAD; ++hh) {
      sum += attn[((size_t)(b * NHEAD + hh) * SEQ_T + t) * DHEAD + d];
    }
    Ms[lr][d] = sum * (1.0f / NHEAD);
  }
  __syncthreads();

  const int c0 = tid * 2;             // cols c0, c0+1
  float a0[16], a1[16];
#pragma unroll
  for (int i = 0; i < 16; ++i) { a0[i] = 0.f; a1[i] = 0.f; }

  for (int d = 0; d < 64; ++d) {
    float2 w = *(const float2*)(Wout + (size_t)d * HIDDEN + c0);
#pragma unroll
    for (int lr = 0; lr < 16; ++lr) {
      float m = Ms[lr][d];
      a0[lr] += m * w.x;
      a1[lr] += m * w.y;
    }
  }
#pragma unroll
  for (int lr = 0; lr < 16; ++lr) {
    float2 v = make_float2(a0[lr], a1[lr]);
    *(float2*)(out + (size_t)(row0 + lr) * HIDDEN + c0) = v;
  }
}

// ---------------------------------------------------------------------------
extern "C" void kernel_launch(void* const* d_in, const int* in_sizes, int n_in,
                              void* d_out, int out_size, void* d_ws, size_t ws_size,
                              hipStream_t stream) {
  const float* x     = (const float*)d_in[0];   // (4,2048,512)
  const float* W_qkv = (const float*)d_in[1];   // (512,1088)
  const float* W_out = (const float*)d_in[2];   // (64,512)

  float* out      = (float*)d_out;                              // (4,2048,512)
  float* attn_vec = out + (size_t)BATCH * SEQ_T * HIDDEN;       // (4,8,2048,64)
  float* qkv      = (float*)d_ws;                               // (8192,1088) = 35.7 MB

  qkv_gemm<<<dim3(64, 17), 256, 0, stream>>>(x, W_qkv, qkv);
  attn_kernel<<<dim3(32, 32), 256, 0, stream>>>(qkv, attn_vec);
  out_gemm<<<dim3(512), 256, 0, stream>>>(attn_vec, W_out, out);
}

// Round 2
// 304.898 us; speedup vs baseline: 2.9129x; 2.9129x over previous
//
#include <hip/hip_runtime.h>
#include <hip/hip_bf16.h>

// Problem constants (reference: InterpretableMultiHeadAttention)
#define NHEAD  8
#define DHEAD  64
#define HIDDEN 512
#define SEQ_T  2048
#define BATCH  4
#define NQKV   1088          // (2*8+1)*64
#define NT     32            // 2048/64 k-tiles

typedef __attribute__((ext_vector_type(8))) short short8;   // 8 x bf16 (4 VGPRs)
typedef __attribute__((ext_vector_type(4))) float f32x4;

// round-to-nearest-even f32 -> bf16 (finite inputs only)
__device__ __forceinline__ unsigned short f2bf(float f) {
  unsigned int u = __float_as_uint(f);
  u += 0x7FFFu + ((u >> 16) & 1u);
  return (unsigned short)(u >> 16);
}

// DPP butterfly reductions over the 16-lane DPP row (lanes with same lane>>4).
// masks {xor1, xor2, mirror-within-8 (=xor7), mirror-within-16 (=xor15)} span GF(2)^4.
#define DPPF(x, ctrl) \
  __int_as_float(__builtin_amdgcn_update_dpp(0, __float_as_int(x), (ctrl), 0xF, 0xF, true))

__device__ __forceinline__ float rmax16(float x) {
  x = fmaxf(x, DPPF(x, 0xB1));   // quad_perm [1,0,3,2]  (xor 1)
  x = fmaxf(x, DPPF(x, 0x4E));   // quad_perm [2,3,0,1]  (xor 2)
  x = fmaxf(x, DPPF(x, 0x141));  // row_half_mirror      (xor 7)
  x = fmaxf(x, DPPF(x, 0x140));  // row_mirror           (xor 15)
  return x;
}
__device__ __forceinline__ float rsum16(float x) {
  x += DPPF(x, 0xB1);
  x += DPPF(x, 0x4E);
  x += DPPF(x, 0x141);
  x += DPPF(x, 0x140);
  return x;
}

// ---------------------------------------------------------------------------
// Kernel 1: qkv = x @ W_qkv, fp32 compute, bf16 store.
// X:(8192,512)  W:(512,1088)  Y:(8192,1088) bf16
// ---------------------------------------------------------------------------
__global__ __launch_bounds__(256) void qkv_gemm(const float* __restrict__ X,
                                                const float* __restrict__ W,
                                                unsigned short* __restrict__ Y) {
  __shared__ float As[16][136];
  __shared__ float Bs[16][68];
  const int bm = blockIdx.x;     // 0..63
  const int bn = blockIdx.y;     // 0..16
  const int tid = threadIdx.x;
  const int tx = tid & 15;
  const int ty = tid >> 4;
  const float* xblk = X + (size_t)bm * 128 * HIDDEN;
  const float* wblk = W + bn * 64;

  float acc[8][4];
#pragma unroll
  for (int i = 0; i < 8; ++i)
#pragma unroll
    for (int j = 0; j < 4; ++j) acc[i][j] = 0.f;

  for (int k0 = 0; k0 < HIDDEN; k0 += 16) {
    float4 av[2];
#pragma unroll
    for (int i = 0; i < 2; ++i) {
      int f = tid + i * 256;
      int m = f >> 2;
      int kk = (f & 3) * 4;
      av[i] = *(const float4*)(xblk + (size_t)m * HIDDEN + k0 + kk);
    }
    const int bkk = tid >> 4;
    const int bn0 = (tid & 15) * 4;
    float4 bv = *(const float4*)(wblk + (size_t)(k0 + bkk) * NQKV + bn0);

    __syncthreads();
#pragma unroll
    for (int i = 0; i < 2; ++i) {
      int f = tid + i * 256;
      int m = f >> 2;
      int kk = (f & 3) * 4;
      As[kk + 0][m] = av[i].x;
      As[kk + 1][m] = av[i].y;
      As[kk + 2][m] = av[i].z;
      As[kk + 3][m] = av[i].w;
    }
    *(float4*)&Bs[bkk][bn0] = bv;
    __syncthreads();

#pragma unroll
    for (int kk = 0; kk < 16; ++kk) {
      float4 a0 = *(const float4*)&As[kk][ty * 8];
      float4 a1 = *(const float4*)&As[kk][ty * 8 + 4];
      float4 b4 = *(const float4*)&Bs[kk][tx * 4];
      float am[8] = {a0.x, a0.y, a0.z, a0.w, a1.x, a1.y, a1.z, a1.w};
      float bb[4] = {b4.x, b4.y, b4.z, b4.w};
#pragma unroll
      for (int i = 0; i < 8; ++i)
#pragma unroll
        for (int j = 0; j < 4; ++j) acc[i][j] += am[i] * bb[j];
    }
  }

#pragma unroll
  for (int i = 0; i < 8; ++i) {
    int row = bm * 128 + ty * 8 + i;
    ushort4 v;
    v.x = f2bf(acc[i][0]); v.y = f2bf(acc[i][1]);
    v.z = f2bf(acc[i][2]); v.w = f2bf(acc[i][3]);
    *(ushort4*)(Y + (size_t)row * NQKV + bn * 64 + tx * 4) = v;
  }
}

// ---------------------------------------------------------------------------
// Kernel 2: vt[b][d][t] = V[b][t][d]  (bf16, 1 MB total)
// ---------------------------------------------------------------------------
__global__ __launch_bounds__(256) void v_transpose(const unsigned short* __restrict__ qkv,
                                                   unsigned short* __restrict__ vt) {
  const int b = blockIdx.x >> 5;
  const int k0 = (blockIdx.x & 31) * 64;
  const int tid = threadIdx.x;
  __shared__ unsigned short Vs[64 * 66];   // pitch 66 -> 2-way max on col reads

  // load 64x64 bf16 tile as dwords (2048 dwords, 8/thread), coalesced
#pragma unroll
  for (int i = 0; i < 8; ++i) {
    int c = tid + i * 256;
    int row = c >> 5;
    int col2 = c & 31;
    unsigned int v = *(const unsigned int*)(qkv + (size_t)(b * SEQ_T + k0 + row) * NQKV + 1024 + col2 * 2);
    *(unsigned int*)&Vs[row * 66 + col2 * 2] = v;
  }
  __syncthreads();

  // write transposed rows, lanes sweep c (coalesced b16 -> merged dwords)
#pragma unroll
  for (int i = 0; i < 16; ++i) {
    int f = tid + i * 256;
    int d = f >> 6;           // wave-uniform per instruction
    int c = f & 63;
    vt[((size_t)b * DHEAD + d) * SEQ_T + k0 + c] = Vs[c * 66 + d];
  }
}

// ---------------------------------------------------------------------------
// Kernel 3: flash attention, bf16 MFMA (16x16x32), fp32 accum.
// block = (bh, pair). Processes q-tiles {pair, 31-pair} -> 33 iters/block.
// wave w owns q-rows [q0+16w, q0+16w+16). Layouts (m89/m97-verified):
//   A[m=lane&15][k=quad*8+j], B[n=lane&15][k=quad*8+j], C col=lane&15,row=quad*4+r
// ---------------------------------------------------------------------------
__global__ __launch_bounds__(256) void attn_mfma(const unsigned short* __restrict__ qkv,
                                                 const unsigned short* __restrict__ vt,
                                                 float* __restrict__ attn_out) {
  const int bh = blockIdx.x;       // 0..31
  const int pair = blockIdx.y;     // 0..15
  const int b = bh >> 3;
  const int h = bh & 7;
  const int tid = threadIdx.x;
  const int wave = tid >> 6;
  const int lane = tid & 63;
  const int quad = lane >> 4;
  const int l15 = lane & 15;

  __shared__ unsigned short Ks[64 * 72];        // K tile, natural [c][d]
  __shared__ unsigned short Vts[64 * 72];       // V^T tile, [d][c]
  __shared__ unsigned short Ps[4 * 16 * 72];    // per-wave P strips [q][c]

  const unsigned short* bq = qkv + (size_t)b * SEQ_T * NQKV;
  const unsigned short* bvt = vt + (size_t)b * DHEAD * SEQ_T;
  const float SC = 0.125f * 1.44269504f;        // qk-scale * log2(e)

  for (int sp = 0; sp < 2; ++sp) {
    const int qt = sp ? (NT - 1 - pair) : pair;
    const int q0 = qt * 64;

    // Q A-frags held in registers for the whole strip
    const unsigned short* qptr = bq + (size_t)(q0 + wave * 16 + l15) * NQKV + h * 64 + quad * 8;
    short8 aq0 = *(const short8*)(qptr);
    short8 aq1 = *(const short8*)(qptr + 32);

    f32x4 o[4];
#pragma unroll
    for (int t = 0; t < 4; ++t) o[t] = (f32x4){0.f, 0.f, 0.f, 0.f};
    float m_run[4] = {-1e30f, -1e30f, -1e30f, -1e30f};
    float l_run[4] = {0.f, 0.f, 0.f, 0.f};

    for (int kt = 0; kt <= qt; ++kt) {
      const int k0 = kt * 64;
      __syncthreads();   // prior iter / prior strip done reading LDS
#pragma unroll
      for (int i = 0; i < 2; ++i) {
        int c = tid + i * 256;
        int row = c >> 3;
        int col8 = (c & 7) * 8;
        short8 kv = *(const short8*)(bq + (size_t)(k0 + row) * NQKV + 512 + h * 64 + col8);
        *(short8*)&Ks[row * 72 + col8] = kv;
        short8 vv = *(const short8*)(bvt + (size_t)row * SEQ_T + k0 + col8);
        *(short8*)&Vts[row * 72 + col8] = vv;
      }
      __syncthreads();

      // ---- S strip = Q K^T (16x64 per wave)
      f32x4 st[4];
#pragma unroll
      for (int t = 0; t < 4; ++t) {
        const unsigned short* kp = &Ks[(l15 + 16 * t) * 72 + quad * 8];
        short8 bk0 = *(const short8*)kp;
        short8 bk1 = *(const short8*)(kp + 32);
        f32x4 acc = (f32x4){0.f, 0.f, 0.f, 0.f};
        acc = __builtin_amdgcn_mfma_f32_16x16x32_bf16(aq0, bk0, acc, 0, 0, 0);
        acc = __builtin_amdgcn_mfma_f32_16x16x32_bf16(aq1, bk1, acc, 0, 0, 0);
        st[t] = acc;
      }

      // ---- scale (+ causal mask on diagonal tile)
#pragma unroll
      for (int t = 0; t < 4; ++t)
#pragma unroll
        for (int r = 0; r < 4; ++r) st[t][r] *= SC;
      if (kt == qt) {
#pragma unroll
        for (int t = 0; t < 4; ++t)
#pragma unroll
          for (int r = 0; r < 4; ++r)
            if (l15 + 16 * t > wave * 16 + quad * 4 + r) st[t][r] = -1e30f;
      }

      // ---- online softmax (per row r; stats replicated across 16-lane row)
      float al[4];
#pragma unroll
      for (int r = 0; r < 4; ++r) {
        float mx = fmaxf(fmaxf(st[0][r], st[1][r]), fmaxf(st[2][r], st[3][r]));
        mx = rmax16(mx);
        float mn = fmaxf(m_run[r], mx);
        al[r] = __builtin_amdgcn_exp2f(m_run[r] - mn);
        m_run[r] = mn;
      }
#pragma unroll
      for (int t = 0; t < 4; ++t)
#pragma unroll
        for (int r = 0; r < 4; ++r)
          st[t][r] = __builtin_amdgcn_exp2f(st[t][r] - m_run[r]);
#pragma unroll
      for (int r = 0; r < 4; ++r) {
        float s = ((st[0][r] + st[1][r]) + (st[2][r] + st[3][r]));
        s = rsum16(s);
        l_run[r] = l_run[r] * al[r] + s;
      }
#pragma unroll
      for (int t = 0; t < 4; ++t)
#pragma unroll
        for (int r = 0; r < 4; ++r) o[t][r] *= al[r];

      // ---- P -> LDS (bf16, per-wave strip; wave-internal dep, no barrier)
#pragma unroll
      for (int t = 0; t < 4; ++t)
#pragma unroll
        for (int r = 0; r < 4; ++r)
          Ps[(wave * 16 + quad * 4 + r) * 72 + l15 + 16 * t] = f2bf(st[t][r]);

      const unsigned short* pp = &Ps[(wave * 16 + l15) * 72 + quad * 8];
      short8 ap0 = *(const short8*)pp;
      short8 ap1 = *(const short8*)(pp + 32);

      // ---- O += P V
#pragma unroll
      for (int t = 0; t < 4; ++t) {
        const unsigned short* vp = &Vts[(l15 + 16 * t) * 72 + quad * 8];
        short8 bv0 = *(const short8*)vp;
        short8 bv1 = *(const short8*)(vp + 32);
        o[t] = __builtin_amdgcn_mfma_f32_16x16x32_bf16(ap0, bv0, o[t], 0, 0, 0);
        o[t] = __builtin_amdgcn_mfma_f32_16x16x32_bf16(ap1, bv1, o[t], 0, 0, 0);
      }
    }

    // ---- epilogue: O /= l, store fp32
    float inv[4];
#pragma unroll
    for (int r = 0; r < 4; ++r) inv[r] = 1.0f / l_run[r];
    const size_t orow = (size_t)bh * SEQ_T + q0 + wave * 16 + quad * 4;
#pragma unroll
    for (int t = 0; t < 4; ++t)
#pragma unroll
      for (int r = 0; r < 4; ++r)
        attn_out[(orow + r) * DHEAD + l15 + 16 * t] = o[t][r] * inv[r];
  }
}

// ---------------------------------------------------------------------------
// Kernel 4: out = mean_h(attn_vec) @ W_out   (unchanged fp32)
// ---------------------------------------------------------------------------
__global__ __launch_bounds__(256) void out_gemm(const float* __restrict__ attn,
                                                const float* __restrict__ Wout,
                                                float* __restrict__ out) {
  const int row0 = blockIdx.x * 16;
  const int tid = threadIdx.x;
  __shared__ float Ms[16][64];

#pragma unroll
  for (int i = 0; i < 4; ++i) {
    int f = tid + i * 256;
    int lr = f >> 6;
    int d = f & 63;
    int row = row0 + lr;
    int b = row >> 11;
    int t = row & 2047;
    float sum = 0.f;
#pragma unroll
    for (int hh = 0; hh < NHEAD; ++hh) {
      sum += attn[((size_t)(b * NHEAD + hh) * SEQ_T + t) * DHEAD + d];
    }
    Ms[lr][d] = sum * (1.0f / NHEAD);
  }
  __syncthreads();

  const int c0 = tid * 2;
  float a0[16], a1[16];
#pragma unroll
  for (int i = 0; i < 16; ++i) { a0[i] = 0.f; a1[i] = 0.f; }

  for (int d = 0; d < 64; ++d) {
    float2 w = *(const float2*)(Wout + (size_t)d * HIDDEN + c0);
#pragma unroll
    for (int lr = 0; lr < 16; ++lr) {
      float m = Ms[lr][d];
      a0[lr] += m * w.x;
      a1[lr] += m * w.y;
    }
  }
#pragma unroll
  for (int lr = 0; lr < 16; ++lr) {
    float2 v = make_float2(a0[lr], a1[lr]);
    *(float2*)(out + (size_t)(row0 + lr) * HIDDEN + c0) = v;
  }
}

// ---------------------------------------------------------------------------
extern "C" void kernel_launch(void* const* d_in, const int* in_sizes, int n_in,
                              void* d_out, int out_size, void* d_ws, size_t ws_size,
                              hipStream_t stream) {
  const float* x     = (const float*)d_in[0];   // (4,2048,512)
  const float* W_qkv = (const float*)d_in[1];   // (512,1088)
  const float* W_out = (const float*)d_in[2];   // (64,512)

  float* out      = (float*)d_out;                              // (4,2048,512)
  float* attn_vec = out + (size_t)BATCH * SEQ_T * HIDDEN;       // (4,8,2048,64)

  unsigned short* qkv = (unsigned short*)d_ws;                  // (8192,1088) bf16 = 17.8 MB
  unsigned short* vt  = qkv + (size_t)BATCH * SEQ_T * NQKV;     // (4,64,2048) bf16 = 1 MB

  qkv_gemm<<<dim3(64, 17), 256, 0, stream>>>(x, W_qkv, qkv);
  v_transpose<<<dim3(BATCH * NT), 256, 0, stream>>>(qkv, vt);
  attn_mfma<<<dim3(32, 16), 256, 0, stream>>>(qkv, vt, attn_vec);
  out_gemm<<<dim3(512), 256, 0, stream>>>(attn_vec, W_out, out);
}

// Round 3
// 191.276 us; speedup vs baseline: 4.6433x; 1.5940x over previous
//
#include <hip/hip_runtime.h>
#include <hip/hip_bf16.h>

// Problem constants (reference: InterpretableMultiHeadAttention)
#define NHEAD  8
#define DHEAD  64
#define HIDDEN 512
#define SEQ_T  2048
#define BATCH  4
#define NQKV   1088          // (2*8+1)*64
#define NT     32            // 2048/64 k-tiles
#define NROWS  (BATCH * SEQ_T)   // 8192

typedef __attribute__((ext_vector_type(8))) short short8;   // 8 x bf16 (4 VGPRs)
typedef __attribute__((ext_vector_type(4))) float f32x4;

// round-to-nearest-even f32 -> bf16 (finite inputs only)
__device__ __forceinline__ unsigned short f2bf(float f) {
  unsigned int u = __float_as_uint(f);
  u += 0x7FFFu + ((u >> 16) & 1u);
  return (unsigned short)(u >> 16);
}

__device__ __forceinline__ void load_lds16(const unsigned short* g, unsigned short* l) {
  __builtin_amdgcn_global_load_lds((const __attribute__((address_space(1))) void*)g,
                                   (__attribute__((address_space(3))) void*)l, 16, 0, 0);
}

// DPP butterfly reductions over the 16-lane DPP row.
#define DPPF(x, ctrl) \
  __int_as_float(__builtin_amdgcn_update_dpp(0, __float_as_int(x), (ctrl), 0xF, 0xF, true))

__device__ __forceinline__ float rmax16(float x) {
  x = fmaxf(x, DPPF(x, 0xB1));   // quad_perm [1,0,3,2]  (xor 1)
  x = fmaxf(x, DPPF(x, 0x4E));   // quad_perm [2,3,0,1]  (xor 2)
  x = fmaxf(x, DPPF(x, 0x141));  // row_half_mirror      (xor 7)
  x = fmaxf(x, DPPF(x, 0x140));  // row_mirror           (xor 15)
  return x;
}
__device__ __forceinline__ float rsum16(float x) {
  x += DPPF(x, 0xB1);
  x += DPPF(x, 0x4E);
  x += DPPF(x, 0x141);
  x += DPPF(x, 0x140);
  return x;
}

// ---------------------------------------------------------------------------
// Prepass A: x fp32 -> bf16.  4,194,304 elements, 8/thread.
// ---------------------------------------------------------------------------
__global__ __launch_bounds__(256) void cvt_x(const float* __restrict__ x,
                                             unsigned short* __restrict__ xb) {
  const size_t i0 = ((size_t)blockIdx.x * 256 + threadIdx.x) * 8;
  float4 a = *(const float4*)(x + i0);
  float4 b = *(const float4*)(x + i0 + 4);
  ushort4 u0, u1;
  u0.x = f2bf(a.x); u0.y = f2bf(a.y); u0.z = f2bf(a.z); u0.w = f2bf(a.w);
  u1.x = f2bf(b.x); u1.y = f2bf(b.y); u1.z = f2bf(b.z); u1.w = f2bf(b.w);
  *(ushort4*)(xb + i0) = u0;
  *(ushort4*)(xb + i0 + 4) = u1;
}

// ---------------------------------------------------------------------------
// Prepass B: Wt[n][k] = bf16(W[k][n]).  W:(512,1088) fp32 -> Wt:(1088,512) bf16
// 64x64 tile transpose through LDS (pitch 65 -> 2-way max on col reads).
// ---------------------------------------------------------------------------
__global__ __launch_bounds__(256) void wt_bf16(const float* __restrict__ W,
                                               unsigned short* __restrict__ Wt) {
  const int n0 = blockIdx.x * 64;   // 0..16
  const int k0 = blockIdx.y * 64;   // 0..7
  const int tid = threadIdx.x;
  __shared__ float T[64 * 65];

#pragma unroll
  for (int i = 0; i < 4; ++i) {
    int f = tid + i * 256;          // float4 index 0..1023
    int r = f >> 4;                 // k row 0..63
    int c4 = (f & 15) * 4;
    float4 v = *(const float4*)(W + (size_t)(k0 + r) * NQKV + n0 + c4);
    T[r * 65 + c4 + 0] = v.x;
    T[r * 65 + c4 + 1] = v.y;
    T[r * 65 + c4 + 2] = v.z;
    T[r * 65 + c4 + 3] = v.w;
  }
  __syncthreads();

#pragma unroll
  for (int i = 0; i < 4; ++i) {
    int f = tid + i * 256;          // ushort4 chunk 0..1023
    int n = f >> 4;                 // 0..63
    int k4 = (f & 15) * 4;
    ushort4 u;
    u.x = f2bf(T[(k4 + 0) * 65 + n]);
    u.y = f2bf(T[(k4 + 1) * 65 + n]);
    u.z = f2bf(T[(k4 + 2) * 65 + n]);
    u.w = f2bf(T[(k4 + 3) * 65 + n]);
    *(ushort4*)(Wt + (size_t)(n0 + n) * HIDDEN + k0 + k4) = u;
  }
}

// ---------------------------------------------------------------------------
// Kernel 1: qkv = xb @ Wt^T via bf16 MFMA, fp32 accum, bf16 store.
// BM=128, BN=64, BK=64, 4 waves; wave owns 32(m) x 64(n).
// global_load_lds(16B) staging; XOR chunk swizzle (chunk^= row&7) kills
// frag-read bank conflicts without padding.
// ---------------------------------------------------------------------------
__global__ __launch_bounds__(256) void qkv_mfma(const unsigned short* __restrict__ Xb,
                                                const unsigned short* __restrict__ Wt,
                                                unsigned short* __restrict__ Y) {
  __shared__ __align__(16) unsigned short As[128 * 64];  // [m][chunk^(m&7)]
  __shared__ __align__(16) unsigned short Bs[64 * 64];   // [n][chunk^(n&7)]
  const int bm = blockIdx.x;     // 0..63
  const int bn = blockIdx.y;     // 0..16
  const int tid = threadIdx.x;
  const int wave = tid >> 6;
  const int lane = tid & 63;
  const int quad = lane >> 4;
  const int l15 = lane & 15;
  const int lrow = lane >> 3;    // staging: 0..7
  const int lchunk = lane & 7;   // staging: physical chunk

  const unsigned short* xrow = Xb + (size_t)bm * 128 * HIDDEN;
  const unsigned short* wrow = Wt + (size_t)bn * 64 * HIDDEN;

  f32x4 acc[2][4];
#pragma unroll
  for (int mt = 0; mt < 2; ++mt)
#pragma unroll
    for (int nt = 0; nt < 4; ++nt) acc[mt][nt] = (f32x4){0.f, 0.f, 0.f, 0.f};

  for (int k0 = 0; k0 < HIDDEN; k0 += 64) {
    __syncthreads();             // prior iter done reading LDS
    // A tile: 128 rows, 16 wave-calls of 8 rows; wave does 4.
#pragma unroll
    for (int c = 0; c < 4; ++c) {
      int call = wave * 4 + c;
      int m = call * 8 + lrow;
      int clog = lchunk ^ lrow;  // (m&7) == lrow
      load_lds16(xrow + (size_t)m * HIDDEN + k0 + clog * 8, &As[call * 512]);
    }
    // B tile: 64 rows, 8 wave-calls; wave does 2.
#pragma unroll
    for (int c = 0; c < 2; ++c) {
      int call = wave * 2 + c;
      int n = call * 8 + lrow;
      int clog = lchunk ^ lrow;
      load_lds16(wrow + (size_t)n * HIDDEN + k0 + clog * 8, &Bs[call * 512]);
    }
    __syncthreads();             // compiler drains vmcnt before barrier

#pragma unroll
    for (int ks = 0; ks < 2; ++ks) {
      short8 a[2], b[4];
#pragma unroll
      for (int mt = 0; mt < 2; ++mt) {
        int m = wave * 32 + mt * 16 + l15;
        int phys = (ks * 4 + quad) ^ (l15 & 7);
        a[mt] = *(const short8*)&As[m * 64 + phys * 8];
      }
#pragma unroll
      for (int nt = 0; nt < 4; ++nt) {
        int n = nt * 16 + l15;
        int phys = (ks * 4 + quad) ^ (l15 & 7);
        b[nt] = *(const short8*)&Bs[n * 64 + phys * 8];
      }
#pragma unroll
      for (int mt = 0; mt < 2; ++mt)
#pragma unroll
        for (int nt = 0; nt < 4; ++nt)
          acc[mt][nt] = __builtin_amdgcn_mfma_f32_16x16x32_bf16(a[mt], b[nt], acc[mt][nt], 0, 0, 0);
    }
  }

  // epilogue: C row=quad*4+r, col=l15 (within 16x16 tile)
#pragma unroll
  for (int mt = 0; mt < 2; ++mt)
#pragma unroll
    for (int r = 0; r < 4; ++r) {
      int row = bm * 128 + wave * 32 + mt * 16 + quad * 4 + r;
#pragma unroll
      for (int nt = 0; nt < 4; ++nt) {
        int col = bn * 64 + nt * 16 + l15;
        Y[(size_t)row * NQKV + col] = f2bf(acc[mt][nt][r]);
      }
    }
}

// ---------------------------------------------------------------------------
// Kernel 2: vt[b][d][t] = V[b][t][d]  (bf16, 1 MB total)
// ---------------------------------------------------------------------------
__global__ __launch_bounds__(256) void v_transpose(const unsigned short* __restrict__ qkv,
                                                   unsigned short* __restrict__ vt) {
  const int b = blockIdx.x >> 5;
  const int k0 = (blockIdx.x & 31) * 64;
  const int tid = threadIdx.x;
  __shared__ unsigned short Vs[64 * 66];

#pragma unroll
  for (int i = 0; i < 8; ++i) {
    int c = tid + i * 256;
    int row = c >> 5;
    int col2 = c & 31;
    unsigned int v = *(const unsigned int*)(qkv + (size_t)(b * SEQ_T + k0 + row) * NQKV + 1024 + col2 * 2);
    *(unsigned int*)&Vs[row * 66 + col2 * 2] = v;
  }
  __syncthreads();

#pragma unroll
  for (int i = 0; i < 16; ++i) {
    int f = tid + i * 256;
    int d = f >> 6;
    int c = f & 63;
    vt[((size_t)b * DHEAD + d) * SEQ_T + k0 + c] = Vs[c * 66 + d];
  }
}

// ---------------------------------------------------------------------------
// Kernel 3: flash attention, bf16 MFMA (16x16x32), fp32 accum.
// block = (bh, pair); processes q-tiles {pair, 31-pair} -> 33 iters/block.
// ---------------------------------------------------------------------------
__global__ __launch_bounds__(256) void attn_mfma(const unsigned short* __restrict__ qkv,
                                                 const unsigned short* __restrict__ vt,
                                                 float* __restrict__ attn_out) {
  const int bh = blockIdx.x;       // 0..31
  const int pair = blockIdx.y;     // 0..15
  const int b = bh >> 3;
  const int h = bh & 7;
  const int tid = threadIdx.x;
  const int wave = tid >> 6;
  const int lane = tid & 63;
  const int quad = lane >> 4;
  const int l15 = lane & 15;

  __shared__ unsigned short Ks[64 * 72];        // K tile, [c][d]
  __shared__ unsigned short Vts[64 * 72];       // V^T tile, [d][c]
  __shared__ unsigned short Ps[4 * 16 * 72];    // per-wave P strips [q][c]

  const unsigned short* bq = qkv + (size_t)b * SEQ_T * NQKV;
  const unsigned short* bvt = vt + (size_t)b * DHEAD * SEQ_T;
  const float SC = 0.125f * 1.44269504f;        // qk-scale * log2(e)

  for (int sp = 0; sp < 2; ++sp) {
    const int qt = sp ? (NT - 1 - pair) : pair;
    const int q0 = qt * 64;

    const unsigned short* qptr = bq + (size_t)(q0 + wave * 16 + l15) * NQKV + h * 64 + quad * 8;
    short8 aq0 = *(const short8*)(qptr);
    short8 aq1 = *(const short8*)(qptr + 32);

    f32x4 o[4];
#pragma unroll
    for (int t = 0; t < 4; ++t) o[t] = (f32x4){0.f, 0.f, 0.f, 0.f};
    float m_run[4] = {-1e30f, -1e30f, -1e30f, -1e30f};
    float l_run[4] = {0.f, 0.f, 0.f, 0.f};

    for (int kt = 0; kt <= qt; ++kt) {
      const int k0 = kt * 64;
      __syncthreads();
#pragma unroll
      for (int i = 0; i < 2; ++i) {
        int c = tid + i * 256;
        int row = c >> 3;
        int col8 = (c & 7) * 8;
        short8 kv = *(const short8*)(bq + (size_t)(k0 + row) * NQKV + 512 + h * 64 + col8);
        *(short8*)&Ks[row * 72 + col8] = kv;
        short8 vv = *(const short8*)(bvt + (size_t)row * SEQ_T + k0 + col8);
        *(short8*)&Vts[row * 72 + col8] = vv;
      }
      __syncthreads();

      f32x4 st[4];
#pragma unroll
      for (int t = 0; t < 4; ++t) {
        const unsigned short* kp = &Ks[(l15 + 16 * t) * 72 + quad * 8];
        short8 bk0 = *(const short8*)kp;
        short8 bk1 = *(const short8*)(kp + 32);
        f32x4 acc = (f32x4){0.f, 0.f, 0.f, 0.f};
        acc = __builtin_amdgcn_mfma_f32_16x16x32_bf16(aq0, bk0, acc, 0, 0, 0);
        acc = __builtin_amdgcn_mfma_f32_16x16x32_bf16(aq1, bk1, acc, 0, 0, 0);
        st[t] = acc;
      }

#pragma unroll
      for (int t = 0; t < 4; ++t)
#pragma unroll
        for (int r = 0; r < 4; ++r) st[t][r] *= SC;
      if (kt == qt) {
#pragma unroll
        for (int t = 0; t < 4; ++t)
#pragma unroll
          for (int r = 0; r < 4; ++r)
            if (l15 + 16 * t > wave * 16 + quad * 4 + r) st[t][r] = -1e30f;
      }

      float al[4];
#pragma unroll
      for (int r = 0; r < 4; ++r) {
        float mx = fmaxf(fmaxf(st[0][r], st[1][r]), fmaxf(st[2][r], st[3][r]));
        mx = rmax16(mx);
        float mn = fmaxf(m_run[r], mx);
        al[r] = __builtin_amdgcn_exp2f(m_run[r] - mn);
        m_run[r] = mn;
      }
#pragma unroll
      for (int t = 0; t < 4; ++t)
#pragma unroll
        for (int r = 0; r < 4; ++r)
          st[t][r] = __builtin_amdgcn_exp2f(st[t][r] - m_run[r]);
#pragma unroll
      for (int r = 0; r < 4; ++r) {
        float s = ((st[0][r] + st[1][r]) + (st[2][r] + st[3][r]));
        s = rsum16(s);
        l_run[r] = l_run[r] * al[r] + s;
      }
#pragma unroll
      for (int t = 0; t < 4; ++t)
#pragma unroll
        for (int r = 0; r < 4; ++r) o[t][r] *= al[r];

#pragma unroll
      for (int t = 0; t < 4; ++t)
#pragma unroll
        for (int r = 0; r < 4; ++r)
          Ps[(wave * 16 + quad * 4 + r) * 72 + l15 + 16 * t] = f2bf(st[t][r]);

      const unsigned short* pp = &Ps[(wave * 16 + l15) * 72 + quad * 8];
      short8 ap0 = *(const short8*)pp;
      short8 ap1 = *(const short8*)(pp + 32);

#pragma unroll
      for (int t = 0; t < 4; ++t) {
        const unsigned short* vp = &Vts[(l15 + 16 * t) * 72 + quad * 8];
        short8 bv0 = *(const short8*)vp;
        short8 bv1 = *(const short8*)(vp + 32);
        o[t] = __builtin_amdgcn_mfma_f32_16x16x32_bf16(ap0, bv0, o[t], 0, 0, 0);
        o[t] = __builtin_amdgcn_mfma_f32_16x16x32_bf16(ap1, bv1, o[t], 0, 0, 0);
      }
    }

    float inv[4];
#pragma unroll
    for (int r = 0; r < 4; ++r) inv[r] = 1.0f / l_run[r];
    const size_t orow = (size_t)bh * SEQ_T + q0 + wave * 16 + quad * 4;
#pragma unroll
    for (int t = 0; t < 4; ++t)
#pragma unroll
      for (int r = 0; r < 4; ++r)
        attn_out[(orow + r) * DHEAD + l15 + 16 * t] = o[t][r] * inv[r];
  }
}

// ---------------------------------------------------------------------------
// Kernel 4: out = mean_h(attn_vec) @ W_out   (fp32)
// ---------------------------------------------------------------------------
__global__ __launch_bounds__(256) void out_gemm(const float* __restrict__ attn,
                                                const float* __restrict__ Wout,
                                                float* __restrict__ out) {
  const int row0 = blockIdx.x * 16;
  const int tid = threadIdx.x;
  __shared__ float Ms[16][64];

#pragma unroll
  for (int i = 0; i < 4; ++i) {
    int f = tid + i * 256;
    int lr = f >> 6;
    int d = f & 63;
    int row = row0 + lr;
    int b = row >> 11;
    int t = row & 2047;
    float sum = 0.f;
#pragma unroll
    for (int hh = 0; hh < NHEAD; ++hh) {
      sum += attn[((size_t)(b * NHEAD + hh) * SEQ_T + t) * DHEAD + d];
    }
    Ms[lr][d] = sum * (1.0f / NHEAD);
  }
  __syncthreads();

  const int c0 = tid * 2;
  float a0[16], a1[16];
#pragma unroll
  for (int i = 0; i < 16; ++i) { a0[i] = 0.f; a1[i] = 0.f; }

  for (int d = 0; d < 64; ++d) {
    float2 w = *(const float2*)(Wout + (size_t)d * HIDDEN + c0);
#pragma unroll
    for (int lr = 0; lr < 16; ++lr) {
      float m = Ms[lr][d];
      a0[lr] += m * w.x;
      a1[lr] += m * w.y;
    }
  }
#pragma unroll
  for (int lr = 0; lr < 16; ++lr) {
    float2 v = make_float2(a0[lr], a1[lr]);
    *(float2*)(out + (size_t)(row0 + lr) * HIDDEN + c0) = v;
  }
}

// ---------------------------------------------------------------------------
extern "C" void kernel_launch(void* const* d_in, const int* in_sizes, int n_in,
                              void* d_out, int out_size, void* d_ws, size_t ws_size,
                              hipStream_t stream) {
  const float* x     = (const float*)d_in[0];   // (4,2048,512)
  const float* W_qkv = (const float*)d_in[1];   // (512,1088)
  const float* W_out = (const float*)d_in[2];   // (64,512)

  float* out      = (float*)d_out;                              // (4,2048,512)
  float* attn_vec = out + (size_t)BATCH * SEQ_T * HIDDEN;       // (4,8,2048,64)

  unsigned short* qkv = (unsigned short*)d_ws;                  // 17.8 MB bf16
  unsigned short* vt  = qkv + (size_t)NROWS * NQKV;             // 1 MB bf16
  unsigned short* xb  = vt + (size_t)BATCH * DHEAD * SEQ_T;     // 8.4 MB bf16
  unsigned short* Wt  = xb + (size_t)NROWS * HIDDEN;            // 1.1 MB bf16

  cvt_x<<<dim3(NROWS * HIDDEN / (256 * 8)), 256, 0, stream>>>(x, xb);
  wt_bf16<<<dim3(17, 8), 256, 0, stream>>>(W_qkv, Wt);
  qkv_mfma<<<dim3(64, 17), 256, 0, stream>>>(xb, Wt, qkv);
  v_transpose<<<dim3(BATCH * NT), 256, 0, stream>>>(qkv, vt);
  attn_mfma<<<dim3(32, 16), 256, 0, stream>>>(qkv, vt, attn_vec);
  out_gemm<<<dim3(512), 256, 0, stream>>>(attn_vec, W_out, out);
}

// Round 4
// 160.245 us; speedup vs baseline: 5.5424x; 1.1936x over previous
//
#include <hip/hip_runtime.h>
#include <hip/hip_bf16.h>

// Problem constants (reference: InterpretableMultiHeadAttention)
#define NHEAD  8
#define DHEAD  64
#define HIDDEN 512
#define SEQ_T  2048
#define BATCH  4
#define NQKV   1088          // (2*8+1)*64
#define NT     32            // 2048/64 k-tiles
#define NROWS  (BATCH * SEQ_T)   // 8192
#define NBH    (BATCH * NHEAD)   // 32

typedef __attribute__((ext_vector_type(8))) short short8;   // 8 x bf16 (4 VGPRs)
typedef __attribute__((ext_vector_type(4))) float f32x4;

// round-to-nearest-even f32 -> bf16 (finite inputs only)
__device__ __forceinline__ unsigned short f2bf(float f) {
  unsigned int u = __float_as_uint(f);
  u += 0x7FFFu + ((u >> 16) & 1u);
  return (unsigned short)(u >> 16);
}
// truncating f32 -> bf16 (for P: values in [0, ~90], bias ~2^-9 rel, OK)
__device__ __forceinline__ unsigned short f2bf_trunc(float f) {
  return (unsigned short)(__float_as_uint(f) >> 16);
}

__device__ __forceinline__ void load_lds16(const unsigned short* g, unsigned short* l) {
  __builtin_amdgcn_global_load_lds((const __attribute__((address_space(1))) void*)g,
                                   (__attribute__((address_space(3))) void*)l, 16, 0, 0);
}

// DPP butterfly sum over the 16-lane DPP row.
#define DPPF(x, ctrl) \
  __int_as_float(__builtin_amdgcn_update_dpp(0, __float_as_int(x), (ctrl), 0xF, 0xF, true))
__device__ __forceinline__ float rsum16(float x) {
  x += DPPF(x, 0xB1);    // quad_perm xor1
  x += DPPF(x, 0x4E);    // quad_perm xor2
  x += DPPF(x, 0x141);   // row_half_mirror
  x += DPPF(x, 0x140);   // row_mirror
  return x;
}

// ---------------------------------------------------------------------------
// Prepass A: x fp32 -> bf16.
// ---------------------------------------------------------------------------
__global__ __launch_bounds__(256) void cvt_x(const float* __restrict__ x,
                                             unsigned short* __restrict__ xb) {
  const size_t i0 = ((size_t)blockIdx.x * 256 + threadIdx.x) * 8;
  float4 a = *(const float4*)(x + i0);
  float4 b = *(const float4*)(x + i0 + 4);
  ushort4 u0, u1;
  u0.x = f2bf(a.x); u0.y = f2bf(a.y); u0.z = f2bf(a.z); u0.w = f2bf(a.w);
  u1.x = f2bf(b.x); u1.y = f2bf(b.y); u1.z = f2bf(b.z); u1.w = f2bf(b.w);
  *(ushort4*)(xb + i0) = u0;
  *(ushort4*)(xb + i0 + 4) = u1;
}

// ---------------------------------------------------------------------------
// Prepass B: Wt[n][k] = bf16(W[k][n])
// ---------------------------------------------------------------------------
__global__ __launch_bounds__(256) void wt_bf16(const float* __restrict__ W,
                                               unsigned short* __restrict__ Wt) {
  const int n0 = blockIdx.x * 64;
  const int k0 = blockIdx.y * 64;
  const int tid = threadIdx.x;
  __shared__ float T[64 * 65];

#pragma unroll
  for (int i = 0; i < 4; ++i) {
    int f = tid + i * 256;
    int r = f >> 4;
    int c4 = (f & 15) * 4;
    float4 v = *(const float4*)(W + (size_t)(k0 + r) * NQKV + n0 + c4);
    T[r * 65 + c4 + 0] = v.x;
    T[r * 65 + c4 + 1] = v.y;
    T[r * 65 + c4 + 2] = v.z;
    T[r * 65 + c4 + 3] = v.w;
  }
  __syncthreads();

#pragma unroll
  for (int i = 0; i < 4; ++i) {
    int f = tid + i * 256;
    int n = f >> 4;
    int k4 = (f & 15) * 4;
    ushort4 u;
    u.x = f2bf(T[(k4 + 0) * 65 + n]);
    u.y = f2bf(T[(k4 + 1) * 65 + n]);
    u.z = f2bf(T[(k4 + 2) * 65 + n]);
    u.w = f2bf(T[(k4 + 3) * 65 + n]);
    *(ushort4*)(Wt + (size_t)(n0 + n) * HIDDEN + k0 + k4) = u;
  }
}

// ---------------------------------------------------------------------------
// Kernel 1: qkv = xb @ Wt^T via bf16 MFMA (unchanged from R3).
// ---------------------------------------------------------------------------
__global__ __launch_bounds__(256) void qkv_mfma(const unsigned short* __restrict__ Xb,
                                                const unsigned short* __restrict__ Wt,
                                                unsigned short* __restrict__ Y) {
  __shared__ __align__(16) unsigned short As[128 * 64];
  __shared__ __align__(16) unsigned short Bs[64 * 64];
  const int bm = blockIdx.x;
  const int bn = blockIdx.y;
  const int tid = threadIdx.x;
  const int wave = tid >> 6;
  const int lane = tid & 63;
  const int quad = lane >> 4;
  const int l15 = lane & 15;
  const int lrow = lane >> 3;
  const int lchunk = lane & 7;

  const unsigned short* xrow = Xb + (size_t)bm * 128 * HIDDEN;
  const unsigned short* wrow = Wt + (size_t)bn * 64 * HIDDEN;

  f32x4 acc[2][4];
#pragma unroll
  for (int mt = 0; mt < 2; ++mt)
#pragma unroll
    for (int nt = 0; nt < 4; ++nt) acc[mt][nt] = (f32x4){0.f, 0.f, 0.f, 0.f};

  for (int k0 = 0; k0 < HIDDEN; k0 += 64) {
    __syncthreads();
#pragma unroll
    for (int c = 0; c < 4; ++c) {
      int call = wave * 4 + c;
      int m = call * 8 + lrow;
      int clog = lchunk ^ lrow;
      load_lds16(xrow + (size_t)m * HIDDEN + k0 + clog * 8, &As[call * 512]);
    }
#pragma unroll
    for (int c = 0; c < 2; ++c) {
      int call = wave * 2 + c;
      int n = call * 8 + lrow;
      int clog = lchunk ^ lrow;
      load_lds16(wrow + (size_t)n * HIDDEN + k0 + clog * 8, &Bs[call * 512]);
    }
    __syncthreads();

#pragma unroll
    for (int ks = 0; ks < 2; ++ks) {
      short8 a[2], b[4];
#pragma unroll
      for (int mt = 0; mt < 2; ++mt) {
        int m = wave * 32 + mt * 16 + l15;
        int phys = (ks * 4 + quad) ^ (l15 & 7);
        a[mt] = *(const short8*)&As[m * 64 + phys * 8];
      }
#pragma unroll
      for (int nt = 0; nt < 4; ++nt) {
        int n = nt * 16 + l15;
        int phys = (ks * 4 + quad) ^ (l15 & 7);
        b[nt] = *(const short8*)&Bs[n * 64 + phys * 8];
      }
#pragma unroll
      for (int mt = 0; mt < 2; ++mt)
#pragma unroll
        for (int nt = 0; nt < 4; ++nt)
          acc[mt][nt] = __builtin_amdgcn_mfma_f32_16x16x32_bf16(a[mt], b[nt], acc[mt][nt], 0, 0, 0);
    }
  }

#pragma unroll
  for (int mt = 0; mt < 2; ++mt)
#pragma unroll
    for (int r = 0; r < 4; ++r) {
      int row = bm * 128 + wave * 32 + mt * 16 + quad * 4 + r;
#pragma unroll
      for (int nt = 0; nt < 4; ++nt) {
        int col = bn * 64 + nt * 16 + l15;
        Y[(size_t)row * NQKV + col] = f2bf(acc[mt][nt][r]);
      }
    }
}

// ---------------------------------------------------------------------------
// Kernel 2: vt[b][d][t] = V[b][t][d]  (bf16)
// ---------------------------------------------------------------------------
__global__ __launch_bounds__(256) void v_transpose(const unsigned short* __restrict__ qkv,
                                                   unsigned short* __restrict__ vt) {
  const int b = blockIdx.x >> 5;
  const int k0 = (blockIdx.x & 31) * 64;
  const int tid = threadIdx.x;
  __shared__ unsigned short Vs[64 * 66];

#pragma unroll
  for (int i = 0; i < 8; ++i) {
    int c = tid + i * 256;
    int row = c >> 5;
    int col2 = c & 31;
    unsigned int v = *(const unsigned int*)(qkv + (size_t)(b * SEQ_T + k0 + row) * NQKV + 1024 + col2 * 2);
    *(unsigned int*)&Vs[row * 66 + col2 * 2] = v;
  }
  __syncthreads();

#pragma unroll
  for (int i = 0; i < 16; ++i) {
    int f = tid + i * 256;
    int d = f >> 6;
    int c = f & 63;
    vt[((size_t)b * DHEAD + d) * SEQ_T + k0 + c] = Vs[c * 66 + d];
  }
}

// ---------------------------------------------------------------------------
// Kernel 3: flash attention pass, streaming softmax (no running max), k-split.
// block = (bh, y): qt = 15-(y>>1) (128-row q-tile), kh = y&1 (k-range half).
// 4 waves; wave owns 2 strips of 16 q-rows (s*64 + wave*16).
// kh=0 -> fp32 partial O into attn slot; kh=1 -> bf16 partial O into pbuf.
// Per-row l sums stored per half. merge_attn combines: O=(O0+O1)/(l0+l1).
// ---------------------------------------------------------------------------
__global__ __launch_bounds__(256, 4) void attn_pass(const unsigned short* __restrict__ qkv,
                                                    const unsigned short* __restrict__ vt,
                                                    float* __restrict__ part0,
                                                    unsigned short* __restrict__ pbuf,
                                                    float* __restrict__ lbuf) {
  const int bh = blockIdx.x;       // 0..31
  const int y = blockIdx.y;        // 0..31
  const int qt = 15 - (y >> 1);    // big tiles dispatched first
  const int kh = y & 1;
  const int b = bh >> 3;
  const int h = bh & 7;
  const int tid = threadIdx.x;
  const int wave = tid >> 6;
  const int lane = tid & 63;
  const int quad = lane >> 4;
  const int l15 = lane & 15;

  // K/V tiles: pitch 64, XOR chunk swizzle (phys = clog ^ (row&7)), staged
  // via global_load_lds.  P: pitch 72 (16B-aligned rows) + additive column
  // rotation (+16*(row>>2) mod 64) -> conflict-free b16 writes.
  __shared__ __align__(16) unsigned short Ks[64 * 64];
  __shared__ __align__(16) unsigned short Vts[64 * 64];
  __shared__ __align__(16) unsigned short Ps[128 * 72];

  const unsigned short* bq = qkv + (size_t)b * SEQ_T * NQKV;
  const unsigned short* bvt = vt + (size_t)b * DHEAD * SEQ_T;
  const float SCl = 0.125f * 1.44269504f;   // qk-scale * log2(e)

  const int q0 = qt * 128;
  const int kbeg = kh ? (qt + 1) : 0;
  const int kend = kh ? (2 * qt + 1) : qt;  // inclusive; qt+1 tiles each half

  // Q A-frags for both strips, held in registers
  short8 aq[2][2];
#pragma unroll
  for (int s = 0; s < 2; ++s) {
    const unsigned short* qp = bq + (size_t)(q0 + s * 64 + wave * 16 + l15) * NQKV + h * 64 + quad * 8;
    aq[s][0] = *(const short8*)qp;
    aq[s][1] = *(const short8*)(qp + 32);
  }

  f32x4 o[2][4];
#pragma unroll
  for (int s = 0; s < 2; ++s)
#pragma unroll
    for (int t = 0; t < 4; ++t) o[s][t] = (f32x4){0.f, 0.f, 0.f, 0.f};
  float l_part[2][4] = {{0.f, 0.f, 0.f, 0.f}, {0.f, 0.f, 0.f, 0.f}};

  const int srow = tid >> 3;          // 0..31 staging row-within-call
  const int sch = (tid & 7) ^ (srow & 7);  // logical chunk to fetch

  for (int kt = kbeg; kt <= kend; ++kt) {
    const int k0 = kt * 64;
    __syncthreads();                  // prior iter done reading LDS
    // stage K (head h) and V^T tiles: 2 calls each, 256 lanes x 16B
#pragma unroll
    for (int c = 0; c < 2; ++c) {
      load_lds16(bq + (size_t)(k0 + c * 32 + srow) * NQKV + 512 + h * 64 + sch * 8,
                 &Ks[c * 2048 + wave * 512]);
      load_lds16(bvt + (size_t)(c * 32 + srow) * SEQ_T + k0 + sch * 8,
                 &Vts[c * 2048 + wave * 512]);
    }
    __syncthreads();                  // drains vmcnt

    const bool needMask = (k0 + 63) > q0;

    // ---- S = Q K^T, exp, P->LDS (per t so st stays transient)
#pragma unroll
    for (int t = 0; t < 4; ++t) {
      const int n = l15 + 16 * t;     // k-col
      const int ph0 = (quad ^ (l15 & 7)) * 8;
      short8 bk0 = *(const short8*)&Ks[n * 64 + ph0];
      short8 bk1 = *(const short8*)&Ks[n * 64 + (ph0 ^ 32)];
#pragma unroll
      for (int s = 0; s < 2; ++s) {
        f32x4 sv = (f32x4){0.f, 0.f, 0.f, 0.f};
        sv = __builtin_amdgcn_mfma_f32_16x16x32_bf16(aq[s][0], bk0, sv, 0, 0, 0);
        sv = __builtin_amdgcn_mfma_f32_16x16x32_bf16(aq[s][1], bk1, sv, 0, 0, 0);
        const int rbase = s * 64 + wave * 16 + quad * 4;
#pragma unroll
        for (int r = 0; r < 4; ++r) {
          float p = __builtin_amdgcn_exp2f(sv[r] * SCl);
          if (needMask) {
            int gcol = k0 + l15 + 16 * t;
            int grow = q0 + rbase + r;
            p = (gcol <= grow) ? p : 0.f;
          }
          l_part[s][r] += p;
          int prow = rbase + r;
          int colp = (l15 + 16 * t + ((prow >> 2) << 4)) & 63;
          Ps[prow * 72 + colp] = f2bf_trunc(p);
        }
      }
    }

    // ---- A-frags of P (wave-private strip; wave-internal dependency)
    short8 ap[2][2];
#pragma unroll
    for (int s = 0; s < 2; ++s) {
      int prow = s * 64 + wave * 16 + l15;
      int rot = ((prow >> 2) << 1) & 7;          // additive chunk rotation
      int c0 = (quad + rot) & 7;
      int c1 = (quad + 4 + rot) & 7;
      ap[s][0] = *(const short8*)&Ps[prow * 72 + c0 * 8];
      ap[s][1] = *(const short8*)&Ps[prow * 72 + c1 * 8];
    }

    // ---- O += P V  (V^T B-frags shared across strips)
#pragma unroll
    for (int t = 0; t < 4; ++t) {
      const int d = l15 + 16 * t;
      const int ph0 = (quad ^ (l15 & 7)) * 8;
      short8 bv0 = *(const short8*)&Vts[d * 64 + ph0];
      short8 bv1 = *(const short8*)&Vts[d * 64 + (ph0 ^ 32)];
#pragma unroll
      for (int s = 0; s < 2; ++s) {
        o[s][t] = __builtin_amdgcn_mfma_f32_16x16x32_bf16(ap[s][0], bv0, o[s][t], 0, 0, 0);
        o[s][t] = __builtin_amdgcn_mfma_f32_16x16x32_bf16(ap[s][1], bv1, o[s][t], 0, 0, 0);
      }
    }
  }

  // ---- epilogue: raw partial O + per-row l (division happens in merge)
#pragma unroll
  for (int s = 0; s < 2; ++s) {
#pragma unroll
    for (int r = 0; r < 4; ++r) {
      float l = rsum16(l_part[s][r]);
      const int trow = q0 + s * 64 + wave * 16 + quad * 4 + r;
      if (l15 == 0) lbuf[kh * (NBH * SEQ_T) + bh * SEQ_T + trow] = l;
      const size_t base = ((size_t)bh * SEQ_T + trow) * DHEAD;
      if (kh == 0) {
#pragma unroll
        for (int t = 0; t < 4; ++t) part0[base + l15 + 16 * t] = o[s][t][r];
      } else {
#pragma unroll
        for (int t = 0; t < 4; ++t) pbuf[base + l15 + 16 * t] = f2bf(o[s][t][r]);
      }
    }
  }
}

// ---------------------------------------------------------------------------
// Kernel 3b: merge partials: attn = (O0 + O1) / (l0 + l1)
// ---------------------------------------------------------------------------
__global__ __launch_bounds__(256) void merge_attn(float* __restrict__ attnv,
                                                  const unsigned short* __restrict__ pbuf,
                                                  const float* __restrict__ lbuf) {
  const int tid = threadIdx.x;
  const int row = blockIdx.x * 16 + (tid >> 4);
  const int d4 = (tid & 15) * 4;
  const float inv = 1.0f / (lbuf[row] + lbuf[NBH * SEQ_T + row]);
  const size_t idx = (size_t)row * DHEAD + d4;
  float4 A = *(const float4*)(attnv + idx);
  ushort4 B = *(const ushort4*)(pbuf + idx);
  float4 o;
  o.x = (A.x + __uint_as_float((unsigned int)B.x << 16)) * inv;
  o.y = (A.y + __uint_as_float((unsigned int)B.y << 16)) * inv;
  o.z = (A.z + __uint_as_float((unsigned int)B.z << 16)) * inv;
  o.w = (A.w + __uint_as_float((unsigned int)B.w << 16)) * inv;
  *(float4*)(attnv + idx) = o;
}

// ---------------------------------------------------------------------------
// Kernel 4: out = mean_h(attn_vec) @ W_out   (fp32)
// ---------------------------------------------------------------------------
__global__ __launch_bounds__(256) void out_gemm(const float* __restrict__ attn,
                                                const float* __restrict__ Wout,
                                                float* __restrict__ out) {
  const int row0 = blockIdx.x * 16;
  const int tid = threadIdx.x;
  __shared__ float Ms[16][64];

#pragma unroll
  for (int i = 0; i < 4; ++i) {
    int f = tid + i * 256;
    int lr = f >> 6;
    int d = f & 63;
    int row = row0 + lr;
    int b = row >> 11;
    int t = row & 2047;
    float sum = 0.f;
#pragma unroll
    for (int hh = 0; hh < NHEAD; ++hh) {
      sum += attn[((size_t)(b * NHEAD + hh) * SEQ_T + t) * DHEAD + d];
    }
    Ms[lr][d] = sum * (1.0f / NHEAD);
  }
  __syncthreads();

  const int c0 = tid * 2;
  float a0[16], a1[16];
#pragma unroll
  for (int i = 0; i < 16; ++i) { a0[i] = 0.f; a1[i] = 0.f; }

  for (int d = 0; d < 64; ++d) {
    float2 w = *(const float2*)(Wout + (size_t)d * HIDDEN + c0);
#pragma unroll
    for (int lr = 0; lr < 16; ++lr) {
      float m = Ms[lr][d];
      a0[lr] += m * w.x;
      a1[lr] += m * w.y;
    }
  }
#pragma unroll
  for (int lr = 0; lr < 16; ++lr) {
    float2 v = make_float2(a0[lr], a1[lr]);
    *(float2*)(out + (size_t)(row0 + lr) * HIDDEN + c0) = v;
  }
}

// ---------------------------------------------------------------------------
extern "C" void kernel_launch(void* const* d_in, const int* in_sizes, int n_in,
                              void* d_out, int out_size, void* d_ws, size_t ws_size,
                              hipStream_t stream) {
  const float* x     = (const float*)d_in[0];   // (4,2048,512)
  const float* W_qkv = (const float*)d_in[1];   // (512,1088)
  const float* W_out = (const float*)d_in[2];   // (64,512)

  float* out      = (float*)d_out;                              // (4,2048,512)
  float* attn_vec = out + (size_t)BATCH * SEQ_T * HIDDEN;       // (4,8,2048,64)

  unsigned short* qkv = (unsigned short*)d_ws;                  // 17.8 MB bf16
  unsigned short* vt  = qkv + (size_t)NROWS * NQKV;             // 1.0 MB bf16
  unsigned short* xb  = vt + (size_t)BATCH * DHEAD * SEQ_T;     // 8.4 MB bf16
  unsigned short* Wt  = xb + (size_t)NROWS * HIDDEN;            // 1.1 MB bf16
  // xb and Wt are dead after qkv_mfma -> overlay attention partials there
  unsigned short* pbuf = xb;                                    // bf16 partial O (exactly xb size)
  float*          lbuf = (float*)Wt;                            // 2 x 65536 l sums (512 KB <= Wt)

  cvt_x<<<dim3(NROWS * HIDDEN / (256 * 8)), 256, 0, stream>>>(x, xb);
  wt_bf16<<<dim3(17, 8), 256, 0, stream>>>(W_qkv, Wt);
  qkv_mfma<<<dim3(64, 17), 256, 0, stream>>>(xb, Wt, qkv);
  v_transpose<<<dim3(BATCH * NT), 256, 0, stream>>>(qkv, vt);
  attn_pass<<<dim3(NBH, 32), 256, 0, stream>>>(qkv, vt, attn_vec, pbuf, lbuf);
  merge_attn<<<dim3(NBH * SEQ_T / 16), 256, 0, stream>>>(attn_vec, pbuf, lbuf);
  out_gemm<<<dim3(512), 256, 0, stream>>>(attn_vec, W_out, out);
}

// Round 5
// 155.361 us; speedup vs baseline: 5.7167x; 1.0314x over previous
//
#include <hip/hip_runtime.h>
#include <hip/hip_bf16.h>

// Problem constants (reference: InterpretableMultiHeadAttention)
#define NHEAD  8
#define DHEAD  64
#define HIDDEN 512
#define SEQ_T  2048
#define BATCH  4
#define NQKV   1088          // (2*8+1)*64
#define NT     32            // 2048/64 k-tiles
#define NROWS  (BATCH * SEQ_T)   // 8192
#define NBH    (BATCH * NHEAD)   // 32
#define QSC    (0.125f * 1.44269504f)   // qk-scale * log2(e), folded into Q

typedef __attribute__((ext_vector_type(8))) short short8;   // 8 x bf16 (4 VGPRs)
typedef __attribute__((ext_vector_type(4))) float f32x4;

// round-to-nearest-even f32 -> bf16 (finite inputs only)
__device__ __forceinline__ unsigned short f2bf(float f) {
  unsigned int u = __float_as_uint(f);
  u += 0x7FFFu + ((u >> 16) & 1u);
  return (unsigned short)(u >> 16);
}

__device__ __forceinline__ void load_lds16(const unsigned short* g, unsigned short* l) {
  __builtin_amdgcn_global_load_lds((const __attribute__((address_space(1))) void*)g,
                                   (__attribute__((address_space(3))) void*)l, 16, 0, 0);
}

// DPP butterfly sum over the 16-lane DPP row.
#define DPPF(x, ctrl) \
  __int_as_float(__builtin_amdgcn_update_dpp(0, __float_as_int(x), (ctrl), 0xF, 0xF, true))
__device__ __forceinline__ float rsum16(float x) {
  x += DPPF(x, 0xB1);    // quad_perm xor1
  x += DPPF(x, 0x4E);    // quad_perm xor2
  x += DPPF(x, 0x141);   // row_half_mirror
  x += DPPF(x, 0x140);   // row_mirror
  return x;
}

// ---------------------------------------------------------------------------
// Prepass A: x fp32 -> bf16.
// ---------------------------------------------------------------------------
__global__ __launch_bounds__(256) void cvt_x(const float* __restrict__ x,
                                             unsigned short* __restrict__ xb) {
  const size_t i0 = ((size_t)blockIdx.x * 256 + threadIdx.x) * 8;
  float4 a = *(const float4*)(x + i0);
  float4 b = *(const float4*)(x + i0 + 4);
  ushort4 u0, u1;
  u0.x = f2bf(a.x); u0.y = f2bf(a.y); u0.z = f2bf(a.z); u0.w = f2bf(a.w);
  u1.x = f2bf(b.x); u1.y = f2bf(b.y); u1.z = f2bf(b.z); u1.w = f2bf(b.w);
  *(ushort4*)(xb + i0) = u0;
  *(ushort4*)(xb + i0 + 4) = u1;
}

// ---------------------------------------------------------------------------
// Prepass B: Wt[n][k] = bf16(W[k][n])
// ---------------------------------------------------------------------------
__global__ __launch_bounds__(256) void wt_bf16(const float* __restrict__ W,
                                               unsigned short* __restrict__ Wt) {
  const int n0 = blockIdx.x * 64;
  const int k0 = blockIdx.y * 64;
  const int tid = threadIdx.x;
  __shared__ float T[64 * 65];

#pragma unroll
  for (int i = 0; i < 4; ++i) {
    int f = tid + i * 256;
    int r = f >> 4;
    int c4 = (f & 15) * 4;
    float4 v = *(const float4*)(W + (size_t)(k0 + r) * NQKV + n0 + c4);
    T[r * 65 + c4 + 0] = v.x;
    T[r * 65 + c4 + 1] = v.y;
    T[r * 65 + c4 + 2] = v.z;
    T[r * 65 + c4 + 3] = v.w;
  }
  __syncthreads();

#pragma unroll
  for (int i = 0; i < 4; ++i) {
    int f = tid + i * 256;
    int n = f >> 4;
    int k4 = (f & 15) * 4;
    ushort4 u;
    u.x = f2bf(T[(k4 + 0) * 65 + n]);
    u.y = f2bf(T[(k4 + 1) * 65 + n]);
    u.z = f2bf(T[(k4 + 2) * 65 + n]);
    u.w = f2bf(T[(k4 + 3) * 65 + n]);
    *(ushort4*)(Wt + (size_t)(n0 + n) * HIDDEN + k0 + k4) = u;
  }
}

// ---------------------------------------------------------------------------
// Kernel 1: qkv = xb @ Wt^T via bf16 MFMA.  1D grid, XCD-aware swizzle:
// XCD (L&7) owns bm in [8*xcd, 8*xcd+8) x all bn -> A+B tiles L2-resident.
// Q columns (bn<8) pre-scaled by QSC so attention needs no score multiply.
// ---------------------------------------------------------------------------
__global__ __launch_bounds__(256) void qkv_mfma(const unsigned short* __restrict__ Xb,
                                                const unsigned short* __restrict__ Wt,
                                                unsigned short* __restrict__ Y) {
  __shared__ __align__(16) unsigned short As[128 * 64];
  __shared__ __align__(16) unsigned short Bs[64 * 64];
  const int L = blockIdx.x;       // 0..1087
  const int slot = L >> 3;        // 0..135
  const int bm = (L & 7) * 8 + (slot & 7);   // 0..63
  const int bn = slot >> 3;                  // 0..16
  const int tid = threadIdx.x;
  const int wave = tid >> 6;
  const int lane = tid & 63;
  const int quad = lane >> 4;
  const int l15 = lane & 15;
  const int lrow = lane >> 3;
  const int lchunk = lane & 7;

  const unsigned short* xrow = Xb + (size_t)bm * 128 * HIDDEN;
  const unsigned short* wrow = Wt + (size_t)bn * 64 * HIDDEN;

  f32x4 acc[2][4];
#pragma unroll
  for (int mt = 0; mt < 2; ++mt)
#pragma unroll
    for (int nt = 0; nt < 4; ++nt) acc[mt][nt] = (f32x4){0.f, 0.f, 0.f, 0.f};

  for (int k0 = 0; k0 < HIDDEN; k0 += 64) {
    __syncthreads();
#pragma unroll
    for (int c = 0; c < 4; ++c) {
      int call = wave * 4 + c;
      int m = call * 8 + lrow;
      int clog = lchunk ^ lrow;
      load_lds16(xrow + (size_t)m * HIDDEN + k0 + clog * 8, &As[call * 512]);
    }
#pragma unroll
    for (int c = 0; c < 2; ++c) {
      int call = wave * 2 + c;
      int n = call * 8 + lrow;
      int clog = lchunk ^ lrow;
      load_lds16(wrow + (size_t)n * HIDDEN + k0 + clog * 8, &Bs[call * 512]);
    }
    __syncthreads();

#pragma unroll
    for (int ks = 0; ks < 2; ++ks) {
      short8 a[2], b[4];
#pragma unroll
      for (int mt = 0; mt < 2; ++mt) {
        int m = wave * 32 + mt * 16 + l15;
        int phys = (ks * 4 + quad) ^ (l15 & 7);
        a[mt] = *(const short8*)&As[m * 64 + phys * 8];
      }
#pragma unroll
      for (int nt = 0; nt < 4; ++nt) {
        int n = nt * 16 + l15;
        int phys = (ks * 4 + quad) ^ (l15 & 7);
        b[nt] = *(const short8*)&Bs[n * 64 + phys * 8];
      }
#pragma unroll
      for (int mt = 0; mt < 2; ++mt)
#pragma unroll
        for (int nt = 0; nt < 4; ++nt)
          acc[mt][nt] = __builtin_amdgcn_mfma_f32_16x16x32_bf16(a[mt], b[nt], acc[mt][nt], 0, 0, 0);
    }
  }

  const float qs = (bn < 8) ? QSC : 1.0f;   // pre-scale Q region
#pragma unroll
  for (int mt = 0; mt < 2; ++mt)
#pragma unroll
    for (int r = 0; r < 4; ++r) {
      int row = bm * 128 + wave * 32 + mt * 16 + quad * 4 + r;
#pragma unroll
      for (int nt = 0; nt < 4; ++nt) {
        int col = bn * 64 + nt * 16 + l15;
        Y[(size_t)row * NQKV + col] = f2bf(acc[mt][nt][r] * qs);
      }
    }
}

// ---------------------------------------------------------------------------
// Kernel 2: vt[b][d][k0+n] = V[b][k0+pi(n)][d], pi(n) = 16*(n&3) + (n>>2).
// The same permutation is applied to P's storage columns in attn_pass, so
// P.V is invariant while P stores become contiguous b64 writes.
// ---------------------------------------------------------------------------
__global__ __launch_bounds__(256) void v_transpose(const unsigned short* __restrict__ qkv,
                                                   unsigned short* __restrict__ vt) {
  const int b = blockIdx.x >> 5;
  const int k0 = (blockIdx.x & 31) * 64;
  const int tid = threadIdx.x;
  __shared__ unsigned short Vs[64 * 66];

#pragma unroll
  for (int i = 0; i < 8; ++i) {
    int c = tid + i * 256;
    int row = c >> 5;
    int col2 = c & 31;
    unsigned int v = *(const unsigned int*)(qkv + (size_t)(b * SEQ_T + k0 + row) * NQKV + 1024 + col2 * 2);
    *(unsigned int*)&Vs[row * 66 + col2 * 2] = v;
  }
  __syncthreads();

#pragma unroll
  for (int i = 0; i < 16; ++i) {
    int f = tid + i * 256;
    int d = f >> 6;
    int n = f & 63;
    int c = ((n & 3) << 4) | (n >> 2);   // pi(n): true kcol
    vt[((size_t)b * DHEAD + d) * SEQ_T + k0 + n] = Vs[c * 66 + d];
  }
}

// ---------------------------------------------------------------------------
// Kernel 3: flash attention pass, streaming softmax (no running max), k-split.
// block = (bh, y): qt = 15-(y>>1) (128-row q-tile), kh = y&1 (k-range half).
// Q pre-scaled by QSC -> p = exp2(S) directly. P stored column-permuted
// (matching vt) as packed b64 writes; read back as A-frags from LDS.
// kh=0 -> fp32 partial O; kh=1 -> bf16 partial O + per-row l sums.
// ---------------------------------------------------------------------------
__global__ __launch_bounds__(256, 4) void attn_pass(const unsigned short* __restrict__ qkv,
                                                    const unsigned short* __restrict__ vt,
                                                    float* __restrict__ part0,
                                                    unsigned short* __restrict__ pbuf,
                                                    float* __restrict__ lbuf) {
  const int bh = blockIdx.x;       // 0..31
  const int y = blockIdx.y;        // 0..31
  const int qt = 15 - (y >> 1);    // big tiles dispatched first
  const int kh = y & 1;
  const int b = bh >> 3;
  const int h = bh & 7;
  const int tid = threadIdx.x;
  const int wave = tid >> 6;
  const int lane = tid & 63;
  const int quad = lane >> 4;
  const int l15 = lane & 15;

  __shared__ __align__(16) unsigned short Ks[64 * 64];   // XOR-swizzled chunks
  __shared__ __align__(16) unsigned short Vts[64 * 64];  // XOR-swizzled chunks
  __shared__ __align__(16) unsigned short Ps[128 * 72];  // pitch 72, permuted cols

  const unsigned short* bq = qkv + (size_t)b * SEQ_T * NQKV;
  const unsigned short* bvt = vt + (size_t)b * DHEAD * SEQ_T;

  const int q0 = qt * 128;
  const int kbeg = kh ? (qt + 1) : 0;
  const int kend = kh ? (2 * qt + 1) : qt;  // inclusive

  // Q A-frags for both strips (pre-scaled by QSC in qkv_mfma)
  short8 aq[2][2];
#pragma unroll
  for (int s = 0; s < 2; ++s) {
    const unsigned short* qp = bq + (size_t)(q0 + s * 64 + wave * 16 + l15) * NQKV + h * 64 + quad * 8;
    aq[s][0] = *(const short8*)qp;
    aq[s][1] = *(const short8*)(qp + 32);
  }

  f32x4 o[2][4];
#pragma unroll
  for (int s = 0; s < 2; ++s)
#pragma unroll
    for (int t = 0; t < 4; ++t) o[s][t] = (f32x4){0.f, 0.f, 0.f, 0.f};
  float l_part[2][4] = {{0.f, 0.f, 0.f, 0.f}, {0.f, 0.f, 0.f, 0.f}};

  const int srow = tid >> 3;               // 0..31 staging row-within-call
  const int sch = (tid & 7) ^ (srow & 7);  // logical chunk to fetch
  const int ph0 = (quad ^ (l15 & 7)) * 8;  // frag-read physical chunk offset

  for (int kt = kbeg; kt <= kend; ++kt) {
    const int k0 = kt * 64;
    __syncthreads();                  // prior iter done reading LDS
#pragma unroll
    for (int c = 0; c < 2; ++c) {
      load_lds16(bq + (size_t)(k0 + c * 32 + srow) * NQKV + 512 + h * 64 + sch * 8,
                 &Ks[c * 2048 + wave * 512]);
      load_lds16(bvt + (size_t)(c * 32 + srow) * SEQ_T + k0 + sch * 8,
                 &Vts[c * 2048 + wave * 512]);
    }
    __syncthreads();                  // drains vmcnt

    const bool needMask = (k0 + 63) > q0;

    // ---- K B-frags once (shared by both strips)
    short8 bk[4][2];
#pragma unroll
    for (int t = 0; t < 4; ++t) {
      const unsigned short* kp = &Ks[(l15 + 16 * t) * 64];
      bk[t][0] = *(const short8*)(kp + ph0);
      bk[t][1] = *(const short8*)(kp + (ph0 ^ 32));
    }

    // ---- per strip: S = Q K^T -> exp2 -> packed P store
#pragma unroll
    for (int s = 0; s < 2; ++s) {
      f32x4 pr[4];
#pragma unroll
      for (int t = 0; t < 4; ++t) {
        f32x4 sv = (f32x4){0.f, 0.f, 0.f, 0.f};
        sv = __builtin_amdgcn_mfma_f32_16x16x32_bf16(aq[s][0], bk[t][0], sv, 0, 0, 0);
        sv = __builtin_amdgcn_mfma_f32_16x16x32_bf16(aq[s][1], bk[t][1], sv, 0, 0, 0);
        pr[t] = sv;
      }
      const int rbase = s * 64 + wave * 16 + quad * 4;
#pragma unroll
      for (int t = 0; t < 4; ++t)
#pragma unroll
        for (int r = 0; r < 4; ++r) {
          float p = __builtin_amdgcn_exp2f(pr[t][r]);
          if (needMask)
            p = (k0 + 16 * t + l15 <= q0 + rbase + r) ? p : 0.f;
          l_part[s][r] += p;
          pr[t][r] = p;
        }
      // pack 4 t-values (contiguous permuted cols 4*l15..+4) -> b64 store
#pragma unroll
      for (int r = 0; r < 4; ++r) {
        uint2 w;
        w.x = __builtin_amdgcn_perm(__float_as_uint(pr[1][r]), __float_as_uint(pr[0][r]), 0x07060302u);
        w.y = __builtin_amdgcn_perm(__float_as_uint(pr[3][r]), __float_as_uint(pr[2][r]), 0x07060302u);
        *(uint2*)&Ps[(rbase + r) * 72 + 4 * l15] = w;
      }
    }

    // ---- V^T B-frags + P A-frags (wave-internal dep for Ps; no barrier)
    short8 bv[4][2];
#pragma unroll
    for (int t = 0; t < 4; ++t) {
      const unsigned short* vp = &Vts[(l15 + 16 * t) * 64];
      bv[t][0] = *(const short8*)(vp + ph0);
      bv[t][1] = *(const short8*)(vp + (ph0 ^ 32));
    }
    short8 ap[2][2];
#pragma unroll
    for (int s = 0; s < 2; ++s) {
      const unsigned short* pp = &Ps[(s * 64 + wave * 16 + l15) * 72];
      ap[s][0] = *(const short8*)(pp + quad * 8);
      ap[s][1] = *(const short8*)(pp + 32 + quad * 8);
    }

    // ---- O += P V
#pragma unroll
    for (int t = 0; t < 4; ++t)
#pragma unroll
      for (int s = 0; s < 2; ++s) {
        o[s][t] = __builtin_amdgcn_mfma_f32_16x16x32_bf16(ap[s][0], bv[t][0], o[s][t], 0, 0, 0);
        o[s][t] = __builtin_amdgcn_mfma_f32_16x16x32_bf16(ap[s][1], bv[t][1], o[s][t], 0, 0, 0);
      }
  }

  // ---- epilogue: raw partial O + per-row l (division happens in merge)
#pragma unroll
  for (int s = 0; s < 2; ++s) {
#pragma unroll
    for (int r = 0; r < 4; ++r) {
      float l = rsum16(l_part[s][r]);
      const int trow = q0 + s * 64 + wave * 16 + quad * 4 + r;
      if (l15 == 0) lbuf[kh * (NBH * SEQ_T) + bh * SEQ_T + trow] = l;
      const size_t base = ((size_t)bh * SEQ_T + trow) * DHEAD;
      if (kh == 0) {
#pragma unroll
        for (int t = 0; t < 4; ++t) part0[base + l15 + 16 * t] = o[s][t][r];
      } else {
#pragma unroll
        for (int t = 0; t < 4; ++t) pbuf[base + l15 + 16 * t] = f2bf(o[s][t][r]);
      }
    }
  }
}

// ---------------------------------------------------------------------------
// Kernel 3b: merge partials: attn = (O0 + O1) / (l0 + l1)
// ---------------------------------------------------------------------------
__global__ __launch_bounds__(256) void merge_attn(float* __restrict__ attnv,
                                                  const unsigned short* __restrict__ pbuf,
                                                  const float* __restrict__ lbuf) {
  const int tid = threadIdx.x;
  const int row = blockIdx.x * 16 + (tid >> 4);
  const int d4 = (tid & 15) * 4;
  const float inv = 1.0f / (lbuf[row] + lbuf[NBH * SEQ_T + row]);
  const size_t idx = (size_t)row * DHEAD + d4;
  float4 A = *(const float4*)(attnv + idx);
  ushort4 B = *(const ushort4*)(pbuf + idx);
  float4 o;
  o.x = (A.x + __uint_as_float((unsigned int)B.x << 16)) * inv;
  o.y = (A.y + __uint_as_float((unsigned int)B.y << 16)) * inv;
  o.z = (A.z + __uint_as_float((unsigned int)B.z << 16)) * inv;
  o.w = (A.w + __uint_as_float((unsigned int)B.w << 16)) * inv;
  *(float4*)(attnv + idx) = o;
}

// ---------------------------------------------------------------------------
// Kernel 4: out = mean_h(attn_vec) @ W_out   (fp32)
// ---------------------------------------------------------------------------
__global__ __launch_bounds__(256) void out_gemm(const float* __restrict__ attn,
                                                const float* __restrict__ Wout,
                                                float* __restrict__ out) {
  const int row0 = blockIdx.x * 16;
  const int tid = threadIdx.x;
  __shared__ float Ms[16][64];

#pragma unroll
  for (int i = 0; i < 4; ++i) {
    int f = tid + i * 256;
    int lr = f >> 6;
    int d = f & 63;
    int row = row0 + lr;
    int b = row >> 11;
    int t = row & 2047;
    float sum = 0.f;
#pragma unroll
    for (int hh = 0; hh < NHEAD; ++hh) {
      sum += attn[((size_t)(b * NHEAD + hh) * SEQ_T + t) * DHEAD + d];
    }
    Ms[lr][d] = sum * (1.0f / NHEAD);
  }
  __syncthreads();

  const int c0 = tid * 2;
  float a0[16], a1[16];
#pragma unroll
  for (int i = 0; i < 16; ++i) { a0[i] = 0.f; a1[i] = 0.f; }

  for (int d = 0; d < 64; ++d) {
    float2 w = *(const float2*)(Wout + (size_t)d * HIDDEN + c0);
#pragma unroll
    for (int lr = 0; lr < 16; ++lr) {
      float m = Ms[lr][d];
      a0[lr] += m * w.x;
      a1[lr] += m * w.y;
    }
  }
#pragma unroll
  for (int lr = 0; lr < 16; ++lr) {
    float2 v = make_float2(a0[lr], a1[lr]);
    *(float2*)(out + (size_t)(row0 + lr) * HIDDEN + c0) = v;
  }
}

// ---------------------------------------------------------------------------
extern "C" void kernel_launch(void* const* d_in, const int* in_sizes, int n_in,
                              void* d_out, int out_size, void* d_ws, size_t ws_size,
                              hipStream_t stream) {
  const float* x     = (const float*)d_in[0];   // (4,2048,512)
  const float* W_qkv = (const float*)d_in[1];   // (512,1088)
  const float* W_out = (const float*)d_in[2];   // (64,512)

  float* out      = (float*)d_out;                              // (4,2048,512)
  float* attn_vec = out + (size_t)BATCH * SEQ_T * HIDDEN;       // (4,8,2048,64)

  unsigned short* qkv = (unsigned short*)d_ws;                  // 17.8 MB bf16
  unsigned short* vt  = qkv + (size_t)NROWS * NQKV;             // 1.0 MB bf16
  unsigned short* xb  = vt + (size_t)BATCH * DHEAD * SEQ_T;     // 8.4 MB bf16
  unsigned short* Wt  = xb + (size_t)NROWS * HIDDEN;            // 1.1 MB bf16
  // xb and Wt are dead after qkv_mfma -> overlay attention partials there
  unsigned short* pbuf = xb;                                    // bf16 partial O
  float*          lbuf = (float*)Wt;                            // 2 x 65536 l sums

  cvt_x<<<dim3(NROWS * HIDDEN / (256 * 8)), 256, 0, stream>>>(x, xb);
  wt_bf16<<<dim3(17, 8), 256, 0, stream>>>(W_qkv, Wt);
  qkv_mfma<<<dim3(64 * 17), 256, 0, stream>>>(xb, Wt, qkv);
  v_transpose<<<dim3(BATCH * NT), 256, 0, stream>>>(qkv, vt);
  attn_pass<<<dim3(NBH, 32), 256, 0, stream>>>(qkv, vt, attn_vec, pbuf, lbuf);
  merge_attn<<<dim3(NBH * SEQ_T / 16), 256, 0, stream>>>(attn_vec, pbuf, lbuf);
  out_gemm<<<dim3(512), 256, 0, stream>>>(attn_vec, W_out, out);
}